// Round 13
// baseline (1308.037 us; speedup 1.0000x reference)
//
#include <hip/hip_runtime.h>
#include <math.h>

// SingleGAP: per-point tiny MLPs + GLOBAL softmax over N (axis 0, faithful bug),
// then attention-weighted sum. out0 = [N][16] x_attn, out1 = [N][160] h2 (flat,
// [F][K] order per point == x2v raw reshape).
//
// K1 (16 lanes/point, ONE f per lane, <64 VGPR target -> 8 waves/SIMD):
//     lane f owns Wf row f (16 regs) and flat chunk [10f,10f+10) == x2 row d=f
//     (5 x float2, 8B@40B-stride: R2-counter-proven clean). x2 row broadcast to
//     the 16-group via ds_swizzle ((d<<5)|0x10); f-reductions via DPP butterfly
//     (0xB1/0x4E/0x141 verified R12, + 0x140 row mirror for the 16-wide step).
//     h2 store = lane's contiguous [10f,10f+10) (R2-verified layout class).
//     Occupancy is the lever: 4 waves/SIMD gave 2.7 TB/s, K3's 58% gives 5.3.
// K2: reduce per-block (m,s) -> global (m,s) per k-slot.
// K3: quad-per-point weighted sum: out0 = softmax(logits) @ x2v.

__device__ __forceinline__ void comb(float& m, float& s, float om, float os) {
  float M = fmaxf(m, om);
  if (M == -INFINITY) return;  // both empty
  s = s * __expf(m - M) + os * __expf(om - M);
  m = M;
}

// Broadcast lane (16group_base + B) to all 16 lanes of its group.
// ds_swizzle BitMode: src = (lane & 0x10) | B  (per 32-lane half).
template <int B>
__device__ __forceinline__ float swz16(float v) {
  return __int_as_float(
      __builtin_amdgcn_ds_swizzle(__float_as_int(v), (B << 5) | 0x10));
}

// DPP move (VALU): result[lane] = v[ctrl-mapped lane].
template <int CTRL>
__device__ __forceinline__ float dppmov(float v) {
  return __int_as_float(__builtin_amdgcn_update_dpp(
      0, __float_as_int(v), CTRL, 0xf, 0xf, true));
}

// 16-lane butterfly sum, all-DPP: quad xor1 (0xB1), quad xor2 (0x4E),
// half-row mirror (0x141, pairs the two quads of each 8), row mirror
// (0x140, pairs the two 8s of each 16). Each step crosses uniform groups.
__device__ __forceinline__ float sum16(float v) {
  v += dppmov<0xB1>(v);
  v += dppmov<0x4E>(v);
  v += dppmov<0x141>(v);
  v += dppmov<0x140>(v);
  return v;
}

__global__ void gap_k1(
    const float* __restrict__ xknn, const float* __restrict__ x,
    const float* __restrict__ Wf, const float* __restrict__ bf,
    const float* __restrict__ W1, const float* __restrict__ b1p,
    float* __restrict__ out, float* __restrict__ partials, int n) {
  __shared__ float s_red[4][10][2];

  const int tid = threadIdx.x;
  const int lane = tid & 63;
  const int wave = tid >> 6;
  const int f = lane & 15;      // owned feature AND owned x2 row d=f
  const int pg = lane >> 4;     // point-subgroup 0..3 within the wave

  // own Wf row f (16 VGPR), W1[f], bf[f]
  float wfo[16];
#pragma unroll
  for (int dq = 0; dq < 4; ++dq) {
    float4 v = *(const float4*)(Wf + (size_t)f * 16 + 4 * dq);
    wfo[4 * dq + 0] = v.x;
    wfo[4 * dq + 1] = v.y;
    wfo[4 * dq + 2] = v.z;
    wfo[4 * dq + 3] = v.w;
  }
  const float w1o = W1[f];
  const float bfo = bf[f];
  // u_own = u[f] = sum_j W1[j] * Wf[j][f]  (column read, prologue-only)
  float u_own = 0.f;
#pragma unroll
  for (int j = 0; j < 16; ++j) u_own = fmaf(W1[j], Wf[j * 16 + f], u_own);
  const float addA = 2.0f * b1p[0];  // logit = tk[k] + a1u + 2*b1 (+sb shift is
                                     // softmax-invariant; tk includes sb, a1u not)

  // online softmax state for k == f (valid for f<10)
  float rm = -INFINITY, rs = 0.f;

  float* out0 = out;                       // [n][16]  (logits now, x_attn later)
  float* out1 = out + (size_t)n * 16;      // [n][160] h2 flat ([F][K] per point)

  const long pt0 = (long)blockIdx.x * 16 + wave * 4 + pg;
  const long pstride = (long)gridDim.x * 16;

  for (long pt = pt0; pt < n; pt += pstride) {
    // own chunk = x2 row d=f: flat [10f,10f+10), 5 x float2 (8B @ 40B stride;
    // all lines fully consumed across the 5 instrs -> HBM-clean, R2-proven)
    const float* rowf = xknn + (size_t)pt * 160 + 10 * f;
    float2 own[5];
#pragma unroll
    for (int j = 0; j < 5; ++j) own[j] = *(const float2*)(rowf + 2 * j);
    const float xo = x[(size_t)pt * 16 + f];

    // acc[k] = bf[f] + sum_d Wf[f][d] * x2[d][k]; row d comes from lane d
    float acc[10];
#pragma unroll
    for (int k = 0; k < 10; ++k) acc[k] = bfo;
#pragma unroll
    for (int d = 0; d < 16; ++d) {
#pragma unroll
      for (int j = 0; j < 10; ++j) {
        const float mine = (j & 1) ? own[j >> 1].y : own[j >> 1].x;
        float xv;
        switch (d) {   // compile-time under full unroll
          case 0:  xv = swz16<0>(mine); break;
          case 1:  xv = swz16<1>(mine); break;
          case 2:  xv = swz16<2>(mine); break;
          case 3:  xv = swz16<3>(mine); break;
          case 4:  xv = swz16<4>(mine); break;
          case 5:  xv = swz16<5>(mine); break;
          case 6:  xv = swz16<6>(mine); break;
          case 7:  xv = swz16<7>(mine); break;
          case 8:  xv = swz16<8>(mine); break;
          case 9:  xv = swz16<9>(mine); break;
          case 10: xv = swz16<10>(mine); break;
          case 11: xv = swz16<11>(mine); break;
          case 12: xv = swz16<12>(mine); break;
          case 13: xv = swz16<13>(mine); break;
          case 14: xv = swz16<14>(mine); break;
          default: xv = swz16<15>(mine); break;
        }
        acc[j] = fmaf(wfo[d], xv, acc[j]);
      }
    }

    // h2 -> out1 flat [F][K]: lane's contiguous [10f,10f+10) (verified layout)
    float* o1 = out1 + (size_t)pt * 160 + 10 * f;
    *(float2*)(o1 + 0) = make_float2(acc[0], acc[1]);
    *(float2*)(o1 + 2) = make_float2(acc[2], acc[3]);
    *(float2*)(o1 + 4) = make_float2(acc[4], acc[5]);
    *(float2*)(o1 + 6) = make_float2(acc[6], acc[7]);
    *(float2*)(o1 + 8) = make_float2(acc[8], acc[9]);

    // tk[k] = sum_f W1[f] h2[f][k]  (includes sb) -- all-DPP 16-lane butterfly
    float tk[10];
#pragma unroll
    for (int k = 0; k < 10; ++k) tk[k] = sum16(w1o * acc[k]);

    // a1u = sum_d u[d] x[d]
    const float a1u = sum16(u_own * xo);
    const float addc = a1u + addA;

    // logit for k == f (select chain; no runtime array index)
    float lj = 0.f;
#pragma unroll
    for (int kk = 0; kk < 10; ++kk) lj = (kk == f) ? (tk[kk] + addc) : lj;

    if (f < 10) {
      out0[(size_t)pt * 16 + f] = lj;   // stash logit; K3 overwrites
      comb(rm, rs, lj, 1.0f);
    }
  }

  // (m,s): combine the 4 point-subgroups (lane bits 4,5), then 4 waves
  {
    float om = __shfl_xor(rm, 16), os = __shfl_xor(rs, 16);
    comb(rm, rs, om, os);
    om = __shfl_xor(rm, 32); os = __shfl_xor(rs, 32);
    comb(rm, rs, om, os);
  }
  if (lane < 10) {
    s_red[wave][lane][0] = rm;
    s_red[wave][lane][1] = rs;
  }
  __syncthreads();
  if (tid < 10) {
    float m = s_red[0][tid][0], s = s_red[0][tid][1];
    comb(m, s, s_red[1][tid][0], s_red[1][tid][1]);
    comb(m, s, s_red[2][tid][0], s_red[2][tid][1]);
    comb(m, s, s_red[3][tid][0], s_red[3][tid][1]);
    partials[(size_t)blockIdx.x * 20 + tid * 2 + 0] = m;
    partials[(size_t)blockIdx.x * 20 + tid * 2 + 1] = s;
  }
}

__global__ __launch_bounds__(256) void gap_k2(const float* __restrict__ part,
                                              int nb, float* __restrict__ fin) {
  const int k = blockIdx.x;   // one block per k-slot
  const int tid = threadIdx.x;
  float m = -INFINITY, s = 0.f;
  for (int i = tid; i < nb; i += 256)
    comb(m, s, part[(size_t)i * 20 + k * 2], part[(size_t)i * 20 + k * 2 + 1]);
#pragma unroll
  for (int mask = 1; mask < 64; mask <<= 1) {
    float om = __shfl_xor(m, mask, 64);
    float os = __shfl_xor(s, mask, 64);
    comb(m, s, om, os);
  }
  __shared__ float sm[4][2];
  const int wave = tid >> 6, lane = tid & 63;
  if (lane == 0) { sm[wave][0] = m; sm[wave][1] = s; }
  __syncthreads();
  if (tid == 0) {
    for (int w = 1; w < 4; ++w) comb(m, s, sm[w][0], sm[w][1]);
    fin[k * 2 + 0] = m;
    fin[k * 2 + 1] = s;
  }
}

// K3: 4 lanes per point; lane (p,q) accumulates features f = 4q..4q+3.
// Reads out1 flat at offset k*16+f == x2v[k][f] (raw-reshape identity).
__global__ __launch_bounds__(256) void gap_k3(const float* __restrict__ fin,
                                              float* __restrict__ out, int n) {
  __shared__ float s_fin[20];
  if (threadIdx.x < 20) s_fin[threadIdx.x] = fin[threadIdx.x];
  __syncthreads();
  float mk[10], rsk[10];
#pragma unroll
  for (int k = 0; k < 10; ++k) {
    mk[k] = s_fin[2 * k];
    rsk[k] = 1.0f / s_fin[2 * k + 1];
  }
  float* out0 = out;
  const float* out1 = out + (size_t)n * 16;
  const int q = threadIdx.x & 3;
  const int pl = threadIdx.x >> 2;           // 64 points per block pass
  for (long i = (long)blockIdx.x * 64 + pl; i < n; i += (long)gridDim.x * 64) {
    float* lrow = out0 + i * 16;
    // all 4 lanes of the quad read the same 64B logit line (L1 broadcast)
    float4 la = *(const float4*)(lrow);
    float4 lb = *(const float4*)(lrow + 4);
    float2 lc = *(const float2*)(lrow + 8);
    float l[10] = {la.x, la.y, la.z, la.w, lb.x, lb.y, lb.z, lb.w, lc.x, lc.y};
    float w[10];
#pragma unroll
    for (int k = 0; k < 10; ++k) w[k] = __expf(l[k] - mk[k]) * rsk[k];
    const float* vrow = out1 + i * 160 + q * 4;
    float4 acc = make_float4(0.f, 0.f, 0.f, 0.f);
#pragma unroll
    for (int k = 0; k < 10; ++k) {
      float4 v = *(const float4*)(vrow + k * 16);
      float wk = w[k];
      acc.x = fmaf(wk, v.x, acc.x);
      acc.y = fmaf(wk, v.y, acc.y);
      acc.z = fmaf(wk, v.z, acc.z);
      acc.w = fmaf(wk, v.w, acc.w);
    }
    // store after all reads (wave-lockstep => no RAW hazard on the logit line)
    *(float4*)(lrow + q * 4) = acc;
  }
}

extern "C" void kernel_launch(void* const* d_in, const int* in_sizes, int n_in,
                              void* d_out, int out_size, void* d_ws, size_t ws_size,
                              hipStream_t stream) {
  const float* xknn = (const float*)d_in[0];
  const float* x    = (const float*)d_in[1];
  const float* Wf   = (const float*)d_in[2];
  const float* bf   = (const float*)d_in[3];
  const float* W1   = (const float*)d_in[4];
  const float* b1   = (const float*)d_in[5];
  float* out = (float*)d_out;
  const int n = in_sizes[1] / 16;  // x is [N][16]

  const int G1 = 2048;
  float* partials = (float*)d_ws;                 // [G1][10][2]
  float* finals = partials + (size_t)G1 * 20;     // [10][2]

  gap_k1<<<G1, 256, 0, stream>>>(xknn, x, Wf, bf, W1, b1, out, partials, n);
  gap_k2<<<10, 256, 0, stream>>>(partials, G1, finals);
  gap_k3<<<2048, 256, 0, stream>>>(finals, out, n);
}

// Round 14
// 1252.689 us; speedup vs baseline: 1.0442x; 1.0442x over previous
//
#include <hip/hip_runtime.h>
#include <math.h>

// SingleGAP: per-point tiny MLPs + GLOBAL softmax over N (axis 0, faithful bug),
// then attention-weighted sum. out0 = [N][16] x_attn, out1 = [N][160] h2 (flat,
// [F][K] order per point == x2v raw reshape).
//
// K1 (R14): 16 lanes/point, ONE f per lane, ~50 VGPR demand, launch_bounds(256)
//     with NO min-waves arg (R11-proven spill-free config; R13's missing bounds
//     made the compiler assume 1024-thread blocks -> 64-cap -> scratch spill ->
//     +4.1GB HBM). Loads are 16B sector-major (R11-proven clean): lane l owns
//     float4 #l, #l+16, (l<8) #l+32 of the 40-float4 row. Distribution via
//     ds_swizzle 16-group broadcast (verified R13); reductions all-DPP sum16
//     (verified R13); tk[] eliminated via fused reduce+select (-10 regs).
//     Stores: h2 at [10f,10f+10) 8B float2s + scalar logits (R2-proven clean).
// K2: reduce per-block (m,s) -> global (m,s) per k-slot.
// K3: quad-per-point weighted sum: out0 = softmax(logits) @ x2v.

__device__ __forceinline__ void comb(float& m, float& s, float om, float os) {
  float M = fmaxf(m, om);
  if (M == -INFINITY) return;  // both empty
  s = s * __expf(m - M) + os * __expf(om - M);
  m = M;
}

// Broadcast lane (16group_base + B) to all 16 lanes of its group.
// ds_swizzle BitMode: src = (lane & 0x10) | B  (per 32-lane half).
template <int B>
__device__ __forceinline__ float swz16(float v) {
  return __int_as_float(
      __builtin_amdgcn_ds_swizzle(__float_as_int(v), (B << 5) | 0x10));
}

// DPP move (VALU): result[lane] = v[ctrl-mapped lane].
template <int CTRL>
__device__ __forceinline__ float dppmov(float v) {
  return __int_as_float(__builtin_amdgcn_update_dpp(
      0, __float_as_int(v), CTRL, 0xf, 0xf, true));
}

// 16-lane butterfly sum, all-DPP (verified R13): quad xor1 (0xB1), quad xor2
// (0x4E), half-row mirror (0x141), row mirror (0x140).
__device__ __forceinline__ float sum16(float v) {
  v += dppmov<0xB1>(v);
  v += dppmov<0x4E>(v);
  v += dppmov<0x141>(v);
  v += dppmov<0x140>(v);
  return v;
}

__device__ __forceinline__ float f4e(const float4& v, int e) {
  return (e == 0) ? v.x : (e == 1) ? v.y : (e == 2) ? v.z : v.w;
}

// swz16 with switch-resolved constant (J&15 is compile-time under full unroll;
// the switch collapses to one instruction -- R13-verified codegen pattern).
__device__ __forceinline__ float swz16sw(float v, int src) {
  switch (src) {
    case 0:  return swz16<0>(v);
    case 1:  return swz16<1>(v);
    case 2:  return swz16<2>(v);
    case 3:  return swz16<3>(v);
    case 4:  return swz16<4>(v);
    case 5:  return swz16<5>(v);
    case 6:  return swz16<6>(v);
    case 7:  return swz16<7>(v);
    case 8:  return swz16<8>(v);
    case 9:  return swz16<9>(v);
    case 10: return swz16<10>(v);
    case 11: return swz16<11>(v);
    case 12: return swz16<12>(v);
    case 13: return swz16<13>(v);
    case 14: return swz16<14>(v);
    default: return swz16<15>(v);
  }
}

__global__ __launch_bounds__(256) void gap_k1(
    const float* __restrict__ xknn, const float* __restrict__ x,
    const float* __restrict__ Wf, const float* __restrict__ bf,
    const float* __restrict__ W1, const float* __restrict__ b1p,
    float* __restrict__ out, float* __restrict__ partials, int n) {
  __shared__ float s_red[4][10][2];

  const int tid = threadIdx.x;
  const int lane = tid & 63;
  const int wave = tid >> 6;
  const int f = lane & 15;      // owned feature; also load-slot id
  const int pg = lane >> 4;     // point-subgroup 0..3 within the wave

  // own Wf row f (16 VGPR), W1[f], bf[f]
  float wfo[16];
#pragma unroll
  for (int dq = 0; dq < 4; ++dq) {
    float4 v = *(const float4*)(Wf + (size_t)f * 16 + 4 * dq);
    wfo[4 * dq + 0] = v.x;
    wfo[4 * dq + 1] = v.y;
    wfo[4 * dq + 2] = v.z;
    wfo[4 * dq + 3] = v.w;
  }
  const float w1o = W1[f];
  const float bfo = bf[f];
  // u_own = u[f] = sum_j W1[j] * Wf[j][f]  (column read, prologue-only)
  float u_own = 0.f;
#pragma unroll
  for (int j = 0; j < 16; ++j) u_own = fmaf(W1[j], Wf[j * 16 + f], u_own);
  const float addA = 2.0f * b1p[0];  // global +sb shift is softmax-invariant

  // online softmax state for k == f (valid for f<10)
  float rm = -INFINITY, rs = 0.f;

  float* out0 = out;                       // [n][16]  (logits now, x_attn later)
  float* out1 = out + (size_t)n * 16;      // [n][160] h2 flat ([F][K] per point)

  const long pt0 = (long)blockIdx.x * 16 + wave * 4 + pg;
  const long pstride = (long)gridDim.x * 16;

  for (long pt = pt0; pt < n; pt += pstride) {
    // 16B sector-major loads (R11-proven clean): the 16-group covers the row's
    // 40 float4s contiguously; lane f holds float4 #f, #f+16, (f<8) #f+32.
    const float* row = xknn + (size_t)pt * 160;
    float4 own[3];
    own[0] = *(const float4*)(row + 4 * f);
    own[1] = *(const float4*)(row + 64 + 4 * f);
    own[2] = own[0];
    if (f < 8) own[2] = *(const float4*)(row + 128 + 4 * f);
    const float xo = x[(size_t)pt * 16 + f];

    // acc[k] = bf[f] + sum_d Wf[f][d] * x2[d][k]; element r = 4J+e lives in
    // lane (J&15), register (J>>4), component e -- all compile-time.
    float acc[10];
#pragma unroll
    for (int k = 0; k < 10; ++k) acc[k] = bfo;
#pragma unroll
    for (int J = 0; J < 40; ++J) {
#pragma unroll
      for (int e = 0; e < 4; ++e) {
        const int r = 4 * J + e, d = r / 10, k = r - d * 10;
        const float mine = f4e(own[J >> 4], e);
        const float xv = swz16sw(mine, J & 15);
        acc[k] = fmaf(wfo[d], xv, acc[k]);
      }
    }

    // h2 -> out1 flat [F][K]: lane's contiguous [10f,10f+10) (R2-proven clean)
    float* o1 = out1 + (size_t)pt * 160 + 10 * f;
    *(float2*)(o1 + 0) = make_float2(acc[0], acc[1]);
    *(float2*)(o1 + 2) = make_float2(acc[2], acc[3]);
    *(float2*)(o1 + 4) = make_float2(acc[4], acc[5]);
    *(float2*)(o1 + 6) = make_float2(acc[6], acc[7]);
    *(float2*)(o1 + 8) = make_float2(acc[8], acc[9]);

    // fused reduce+select: lane f keeps only tk[f] (no tk[] array, -10 regs)
    float lj = 0.f;
#pragma unroll
    for (int k = 0; k < 10; ++k) {
      const float s = sum16(w1o * acc[k]);   // = sb + a2[k], all lanes
      lj = (k == f) ? s : lj;
    }
    const float a1u = sum16(u_own * xo);
    lj += a1u + addA;

    if (f < 10) {
      out0[(size_t)pt * 16 + f] = lj;   // stash logit; K3 overwrites
      comb(rm, rs, lj, 1.0f);
    }
  }

  // (m,s): combine the 4 point-subgroups (lane bits 4,5), then 4 waves
  {
    float om = __shfl_xor(rm, 16), os = __shfl_xor(rs, 16);
    comb(rm, rs, om, os);
    om = __shfl_xor(rm, 32); os = __shfl_xor(rs, 32);
    comb(rm, rs, om, os);
  }
  if (lane < 10) {
    s_red[wave][lane][0] = rm;
    s_red[wave][lane][1] = rs;
  }
  __syncthreads();
  if (tid < 10) {
    float m = s_red[0][tid][0], s = s_red[0][tid][1];
    comb(m, s, s_red[1][tid][0], s_red[1][tid][1]);
    comb(m, s, s_red[2][tid][0], s_red[2][tid][1]);
    comb(m, s, s_red[3][tid][0], s_red[3][tid][1]);
    partials[(size_t)blockIdx.x * 20 + tid * 2 + 0] = m;
    partials[(size_t)blockIdx.x * 20 + tid * 2 + 1] = s;
  }
}

__global__ __launch_bounds__(256) void gap_k2(const float* __restrict__ part,
                                              int nb, float* __restrict__ fin) {
  const int k = blockIdx.x;   // one block per k-slot
  const int tid = threadIdx.x;
  float m = -INFINITY, s = 0.f;
  for (int i = tid; i < nb; i += 256)
    comb(m, s, part[(size_t)i * 20 + k * 2], part[(size_t)i * 20 + k * 2 + 1]);
#pragma unroll
  for (int mask = 1; mask < 64; mask <<= 1) {
    float om = __shfl_xor(m, mask, 64);
    float os = __shfl_xor(s, mask, 64);
    comb(m, s, om, os);
  }
  __shared__ float sm[4][2];
  const int wave = tid >> 6, lane = tid & 63;
  if (lane == 0) { sm[wave][0] = m; sm[wave][1] = s; }
  __syncthreads();
  if (tid == 0) {
    for (int w = 1; w < 4; ++w) comb(m, s, sm[w][0], sm[w][1]);
    fin[k * 2 + 0] = m;
    fin[k * 2 + 1] = s;
  }
}

// K3: 4 lanes per point; lane (p,q) accumulates features f = 4q..4q+3.
// Reads out1 flat at offset k*16+f == x2v[k][f] (raw-reshape identity).
__global__ __launch_bounds__(256) void gap_k3(const float* __restrict__ fin,
                                              float* __restrict__ out, int n) {
  __shared__ float s_fin[20];
  if (threadIdx.x < 20) s_fin[threadIdx.x] = fin[threadIdx.x];
  __syncthreads();
  float mk[10], rsk[10];
#pragma unroll
  for (int k = 0; k < 10; ++k) {
    mk[k] = s_fin[2 * k];
    rsk[k] = 1.0f / s_fin[2 * k + 1];
  }
  float* out0 = out;
  const float* out1 = out + (size_t)n * 16;
  const int q = threadIdx.x & 3;
  const int pl = threadIdx.x >> 2;           // 64 points per block pass
  for (long i = (long)blockIdx.x * 64 + pl; i < n; i += (long)gridDim.x * 64) {
    float* lrow = out0 + i * 16;
    // all 4 lanes of the quad read the same 64B logit line (L1 broadcast)
    float4 la = *(const float4*)(lrow);
    float4 lb = *(const float4*)(lrow + 4);
    float2 lc = *(const float2*)(lrow + 8);
    float l[10] = {la.x, la.y, la.z, la.w, lb.x, lb.y, lb.z, lb.w, lc.x, lc.y};
    float w[10];
#pragma unroll
    for (int k = 0; k < 10; ++k) w[k] = __expf(l[k] - mk[k]) * rsk[k];
    const float* vrow = out1 + i * 160 + q * 4;
    float4 acc = make_float4(0.f, 0.f, 0.f, 0.f);
#pragma unroll
    for (int k = 0; k < 10; ++k) {
      float4 v = *(const float4*)(vrow + k * 16);
      float wk = w[k];
      acc.x = fmaf(wk, v.x, acc.x);
      acc.y = fmaf(wk, v.y, acc.y);
      acc.z = fmaf(wk, v.z, acc.z);
      acc.w = fmaf(wk, v.w, acc.w);
    }
    // store after all reads (wave-lockstep => no RAW hazard on the logit line)
    *(float4*)(lrow + q * 4) = acc;
  }
}

extern "C" void kernel_launch(void* const* d_in, const int* in_sizes, int n_in,
                              void* d_out, int out_size, void* d_ws, size_t ws_size,
                              hipStream_t stream) {
  const float* xknn = (const float*)d_in[0];
  const float* x    = (const float*)d_in[1];
  const float* Wf   = (const float*)d_in[2];
  const float* bf   = (const float*)d_in[3];
  const float* W1   = (const float*)d_in[4];
  const float* b1   = (const float*)d_in[5];
  float* out = (float*)d_out;
  const int n = in_sizes[1] / 16;  // x is [N][16]

  const int G1 = 2048;
  float* partials = (float*)d_ws;                 // [G1][10][2]
  float* finals = partials + (size_t)G1 * 20;     // [10][2]

  gap_k1<<<G1, 256, 0, stream>>>(xknn, x, Wf, bf, W1, b1, out, partials, n);
  gap_k2<<<10, 256, 0, stream>>>(partials, G1, finals);
  gap_k3<<<2048, 256, 0, stream>>>(finals, out, n);
}